// Round 6
// baseline (468.200 us; speedup 1.0000x reference)
//
#include <hip/hip_runtime.h>
#include <math.h>

#define N_ROWS 131072
#define DIMS 64
#define K_CODES 512
#define ARG_BLOCKS (N_ROWS / 256)  // 512 blocks, 1 row per thread

// ---------------- K0: zero bins + c2 via numpy-pairwise (bitwise) --------
__global__ __launch_bounds__(256) void vq_init(const float* __restrict__ codebook,
                                               int* __restrict__ bins,
                                               float* __restrict__ c2g) {
  #pragma clang fp contract(off)
  const int t = threadIdx.x;
  for (int b = t; b < K_CODES; b += 256) bins[b] = 0;
  // numpy pairwise_sum, n=64: 8 accumulators over stride-8 lanes, then fixed tree.
  // (scalar loads here are fine: this kernel is 2 rows/thread, ~3 µs total)
  for (int k = t; k < K_CODES; k += 256) {
    const float* cr = codebook + k * DIMS;
    float r0 = cr[0] * cr[0], r1 = cr[1] * cr[1], r2 = cr[2] * cr[2], r3 = cr[3] * cr[3];
    float r4 = cr[4] * cr[4], r5 = cr[5] * cr[5], r6 = cr[6] * cr[6], r7 = cr[7] * cr[7];
    for (int i = 8; i < 64; i += 8) {
      r0 += cr[i + 0] * cr[i + 0]; r1 += cr[i + 1] * cr[i + 1];
      r2 += cr[i + 2] * cr[i + 2]; r3 += cr[i + 3] * cr[i + 3];
      r4 += cr[i + 4] * cr[i + 4]; r5 += cr[i + 5] * cr[i + 5];
      r6 += cr[i + 6] * cr[i + 6]; r7 += cr[i + 7] * cr[i + 7];
    }
    c2g[k] = ((r0 + r1) + (r2 + r3)) + ((r4 + r5) + (r6 + r7));
  }
}

// ---------------- K1: fused argmin + outputs. NO LDS, NO local arrays. ----------
// 1 row per lane held in 16 NAMED float4 values (X0..X15) — SSA values, never an
// alloca, so they are VGPRs regardless of SROA/unroll pass ordering (rounds 4/5
// showed float xf[64] spills to scratch: VGPR=52, +36MB scratch writes).
// Codebook/c2 indices are wave-uniform -> s_load into SGPRs; zero LDS traffic.
// Numerics (bitwise np): M = sequential fmaf over ascending d; d2 = (x2 - 2M) + c2;
// strict < with ascending k == np first-index argmin.
__global__ __launch_bounds__(256, 2) void vq_argmin(const float* __restrict__ latents,
                                                    const float* __restrict__ codebook,
                                                    const float* __restrict__ c2g,
                                                    float* __restrict__ out_codes,
                                                    int* __restrict__ bins,
                                                    float* __restrict__ out_st,
                                                    double* __restrict__ loss_part) {
  #pragma clang fp contract(off)
  const int t = threadIdx.x;
  const int row = blockIdx.x * 256 + t;

  const float4* xr = (const float4*)(latents + (size_t)row * DIMS);
#define LOADX(p) const float4 X##p = xr[p];
  LOADX(0) LOADX(1) LOADX(2) LOADX(3) LOADX(4) LOADX(5) LOADX(6) LOADX(7)
  LOADX(8) LOADX(9) LOADX(10) LOADX(11) LOADX(12) LOADX(13) LOADX(14) LOADX(15)
#undef LOADX

  // x2: numpy pairwise (n=64). a_d = fl(x_d^2); r_j sums a_{j}, a_{j+8}, ..., a_{j+56}
  // in ascending order (contract OFF => separate mul+add); then the fixed tree.
  float r0 = X0.x * X0.x, r1 = X0.y * X0.y, r2 = X0.z * X0.z, r3 = X0.w * X0.w;
  float r4 = X1.x * X1.x, r5 = X1.y * X1.y, r6 = X1.z * X1.z, r7 = X1.w * X1.w;
#define ACC8(A, B)                                              \
  r0 += A.x * A.x; r1 += A.y * A.y; r2 += A.z * A.z; r3 += A.w * A.w; \
  r4 += B.x * B.x; r5 += B.y * B.y; r6 += B.z * B.z; r7 += B.w * B.w;
  ACC8(X2, X3) ACC8(X4, X5) ACC8(X6, X7) ACC8(X8, X9)
  ACC8(X10, X11) ACC8(X12, X13) ACC8(X14, X15)
#undef ACC8
  const float xn2 = ((r0 + r1) + (r2 + r3)) + ((r4 + r5) + (r6 + r7));

  float m1 = __builtin_inff();
  int i1 = 0x7fffffff;
  const float4* cb4 = (const float4*)codebook;

#define STEP(p)                                   \
  { const float4 c = cr[p];                       \
    acc = fmaf(X##p.x, c.x, acc);                 \
    acc = fmaf(X##p.y, c.y, acc);                 \
    acc = fmaf(X##p.z, c.z, acc);                 \
    acc = fmaf(X##p.w, c.w, acc); }
  #pragma unroll 8
  for (int k = 0; k < K_CODES; ++k) {
    const float4* cr = cb4 + (size_t)k * 16;      // wave-uniform -> s_load
    float acc = 0.f;
    STEP(0) STEP(1) STEP(2) STEP(3) STEP(4) STEP(5) STEP(6) STEP(7)
    STEP(8) STEP(9) STEP(10) STEP(11) STEP(12) STEP(13) STEP(14) STEP(15)
    const float s = (xn2 - 2.0f * acc) + c2g[k];  // two rounded fp32 ops (2*acc exact)
    if (s < m1) { m1 = s; i1 = k; }               // strict <, k ascending: first index
  }
#undef STEP

  out_codes[row] = (float)i1;   // coalesced
  atomicAdd(&bins[i1], 1);

  // fused outputs: gather q (codebook L1/L2-hot), STE write, fp64 loss partial.
  double dacc = 0.0;
  const float4* q4 = cb4 + (size_t)i1 * 16;       // per-lane divergent, cache-hot
  float4* o4 = (float4*)(out_st + (size_t)row * DIMS);
#define EPI(p)                                                            \
  { const float4 q = q4[p]; float4 o;                                     \
    o.x = X##p.x + (q.x - X##p.x); o.y = X##p.y + (q.y - X##p.y);         \
    o.z = X##p.z + (q.z - X##p.z); o.w = X##p.w + (q.w - X##p.w);         \
    o4[p] = o;                                                            \
    const float dx = X##p.x - q.x, dy = X##p.y - q.y;                     \
    const float dz = X##p.z - q.z, dw = X##p.w - q.w;                     \
    dacc += (double)dx * (double)dx; dacc += (double)dy * (double)dy;     \
    dacc += (double)dz * (double)dz; dacc += (double)dw * (double)dw; }
  EPI(0) EPI(1) EPI(2) EPI(3) EPI(4) EPI(5) EPI(6) EPI(7)
  EPI(8) EPI(9) EPI(10) EPI(11) EPI(12) EPI(13) EPI(14) EPI(15)
#undef EPI

  #pragma unroll
  for (int off = 32; off > 0; off >>= 1) dacc += __shfl_down(dacc, off);
  __shared__ double wsum[4];
  if ((t & 63) == 0) wsum[t >> 6] = dacc;
  __syncthreads();
  if (t == 0) loss_part[blockIdx.x] = wsum[0] + wsum[1] + wsum[2] + wsum[3];
}

// ---------------- K2: reduce loss partials + perplexity + scalar outputs ----------
__global__ __launch_bounds__(512) void vq_finalize(const int* __restrict__ bins,
                                                   const double* __restrict__ loss_part,
                                                   float* __restrict__ out3) {
  __shared__ double red[512];
  __shared__ double redl[512];
  const int t = threadIdx.x;
  const double p = (double)bins[t] / 131072.0;
  red[t] = -p * log(p + 1e-10);
  redl[t] = loss_part[t];
  __syncthreads();
  for (int s = 256; s > 0; s >>= 1) {
    if (t < s) { red[t] += red[t + s]; redl[t] += redl[t + s]; }
    __syncthreads();
  }
  if (t == 0) {
    const double mean = redl[0] / 8388608.0;
    out3[0] = (float)(0.25 * mean);  // commitment * COMMITMENT_COST
    out3[1] = (float)mean;           // codebook_loss (same squares bitwise)
    out3[2] = (float)exp(red[0]);    // perplexity
  }
}

extern "C" void kernel_launch(void* const* d_in, const int* in_sizes, int n_in,
                              void* d_out, int out_size, void* d_ws, size_t ws_size,
                              hipStream_t stream) {
  const float* latents = (const float*)d_in[0];
  const float* codebook = (const float*)d_in[1];

  float* out = (float*)d_out;
  float* out_st = out;                                   // 8388608
  float* out_codes = out + (size_t)N_ROWS * DIMS;        // 131072 (codes as float)
  float* out3 = out_codes + N_ROWS;                      // 3 scalars

  char* ws = (char*)d_ws;
  double* loss_part = (double*)ws;               // [0, 4096)   512 slots
  int* bins = (int*)(ws + 4096);                 // [4096, 6144)
  float* c2g = (float*)(ws + 6144);              // [6144, 8192)

  hipLaunchKernelGGL(vq_init, dim3(1), dim3(256), 0, stream,
                     codebook, bins, c2g);
  hipLaunchKernelGGL(vq_argmin, dim3(ARG_BLOCKS), dim3(256), 0, stream,
                     latents, codebook, c2g, out_codes, bins, out_st, loss_part);
  hipLaunchKernelGGL(vq_finalize, dim3(1), dim3(512), 0, stream,
                     bins, loss_part, out3);
}

// Round 7
// 390.668 us; speedup vs baseline: 1.1985x; 1.1985x over previous
//
#include <hip/hip_runtime.h>
#include <math.h>

#define N_ROWS 131072
#define DIMS 64
#define K_CODES 512
#define ARG_BLOCKS (N_ROWS / 256)  // 512 blocks, 1 row per thread

// ---------------- K0: zero bins + c2 via numpy-pairwise (bitwise) --------
__global__ __launch_bounds__(256) void vq_init(const float* __restrict__ codebook,
                                               int* __restrict__ bins,
                                               float* __restrict__ c2g) {
  #pragma clang fp contract(off)
  const int t = threadIdx.x;
  for (int b = t; b < K_CODES; b += 256) bins[b] = 0;
  for (int k = t; k < K_CODES; k += 256) {
    const float* cr = codebook + k * DIMS;
    float r0 = cr[0] * cr[0], r1 = cr[1] * cr[1], r2 = cr[2] * cr[2], r3 = cr[3] * cr[3];
    float r4 = cr[4] * cr[4], r5 = cr[5] * cr[5], r6 = cr[6] * cr[6], r7 = cr[7] * cr[7];
    for (int i = 8; i < 64; i += 8) {
      r0 += cr[i + 0] * cr[i + 0]; r1 += cr[i + 1] * cr[i + 1];
      r2 += cr[i + 2] * cr[i + 2]; r3 += cr[i + 3] * cr[i + 3];
      r4 += cr[i + 4] * cr[i + 4]; r5 += cr[i + 5] * cr[i + 5];
      r6 += cr[i + 6] * cr[i + 6]; r7 += cr[i + 7] * cr[i + 7];
    }
    c2g[k] = ((r0 + r1) + (r2 + r3)) + ((r4 + r5) + (r6 + r7));
  }
}

// ---------------- K1: fused argmin + outputs ----------------
// 1 row/lane in 16 named float4 (X0..X15). k-loop: 8 codes per outer iter,
// 16 explicit d4 steps; each step stages only 8 uniform float4 (32 SGPRs) --
// bounded scalar staging that FITS the ~102-SGPR budget (r6's unroll-8 full-code
// staging = 512 floats forced VGPR staging -> X spilled to scratch: VGPR=52,
// +36MB scratch writes). All accs are named scalars: zero allocas anywhere.
// amdgpu_waves_per_eu(2,2): grid is 2 blocks/CU; don't shrink regs for more waves.
// Numerics (bitwise np): per (row,code) one fmaf chain over ascending d;
// d2 = (x2 - 2M) + c2 (two rounded ops); strict < ascending k = np first-index.
__global__ __launch_bounds__(256)
__attribute__((amdgpu_waves_per_eu(2, 2)))
void vq_argmin(const float* __restrict__ latents,
               const float* __restrict__ codebook,
               const float* __restrict__ c2g,
               float* __restrict__ out_codes,
               int* __restrict__ bins,
               float* __restrict__ out_st,
               double* __restrict__ loss_part) {
  #pragma clang fp contract(off)
  const int t = threadIdx.x;
  const int row = blockIdx.x * 256 + t;

  const float4* xr = (const float4*)(latents + (size_t)row * DIMS);
#define LOADX(p) const float4 X##p = xr[p];
  LOADX(0) LOADX(1) LOADX(2) LOADX(3) LOADX(4) LOADX(5) LOADX(6) LOADX(7)
  LOADX(8) LOADX(9) LOADX(10) LOADX(11) LOADX(12) LOADX(13) LOADX(14) LOADX(15)
#undef LOADX

  // x2: numpy pairwise (n=64): a_d = fl(x_d^2), stride-8 chains ascending, tree.
  float r0 = X0.x * X0.x, r1 = X0.y * X0.y, r2 = X0.z * X0.z, r3 = X0.w * X0.w;
  float r4 = X1.x * X1.x, r5 = X1.y * X1.y, r6 = X1.z * X1.z, r7 = X1.w * X1.w;
#define ACC8(A, B)                                                    \
  r0 += A.x * A.x; r1 += A.y * A.y; r2 += A.z * A.z; r3 += A.w * A.w; \
  r4 += B.x * B.x; r5 += B.y * B.y; r6 += B.z * B.z; r7 += B.w * B.w;
  ACC8(X2, X3) ACC8(X4, X5) ACC8(X6, X7) ACC8(X8, X9)
  ACC8(X10, X11) ACC8(X12, X13) ACC8(X14, X15)
#undef ACC8
  const float xn2 = ((r0 + r1) + (r2 + r3)) + ((r4 + r5) + (r6 + r7));

  float m1 = __builtin_inff();
  int i1 = 0x7fffffff;
  const float4* cb4 = (const float4*)codebook;

  for (int k0 = 0; k0 < K_CODES; k0 += 8) {
    const float4* ck = cb4 + (size_t)k0 * 16;  // wave-uniform base
    float a0 = 0.f, a1 = 0.f, a2 = 0.f, a3 = 0.f;
    float a4 = 0.f, a5 = 0.f, a6 = 0.f, a7 = 0.f;
    // One d4 step: 8 uniform float4 loads (-> s_load_dwordx4, 32 SGPRs live)
    // + 32 fmaf. d ascends with p across steps -> bitwise sgemm chain per code.
#define FMA4(j, cj) \
    a##j = fmaf(X##_P.x, cj.x, a##j); a##j = fmaf(X##_P.y, cj.y, a##j); \
    a##j = fmaf(X##_P.z, cj.z, a##j); a##j = fmaf(X##_P.w, cj.w, a##j);
#define D4STEP(p)                                                        \
    { const float4 cA = ck[0 * 16 + p], cB = ck[1 * 16 + p];             \
      const float4 cC = ck[2 * 16 + p], cD = ck[3 * 16 + p];             \
      const float4 cE = ck[4 * 16 + p], cF = ck[5 * 16 + p];             \
      const float4 cG = ck[6 * 16 + p], cH = ck[7 * 16 + p];             \
      a0 = fmaf(X##p.x, cA.x, a0); a0 = fmaf(X##p.y, cA.y, a0);          \
      a0 = fmaf(X##p.z, cA.z, a0); a0 = fmaf(X##p.w, cA.w, a0);          \
      a1 = fmaf(X##p.x, cB.x, a1); a1 = fmaf(X##p.y, cB.y, a1);          \
      a1 = fmaf(X##p.z, cB.z, a1); a1 = fmaf(X##p.w, cB.w, a1);          \
      a2 = fmaf(X##p.x, cC.x, a2); a2 = fmaf(X##p.y, cC.y, a2);          \
      a2 = fmaf(X##p.z, cC.z, a2); a2 = fmaf(X##p.w, cC.w, a2);          \
      a3 = fmaf(X##p.x, cD.x, a3); a3 = fmaf(X##p.y, cD.y, a3);          \
      a3 = fmaf(X##p.z, cD.z, a3); a3 = fmaf(X##p.w, cD.w, a3);          \
      a4 = fmaf(X##p.x, cE.x, a4); a4 = fmaf(X##p.y, cE.y, a4);          \
      a4 = fmaf(X##p.z, cE.z, a4); a4 = fmaf(X##p.w, cE.w, a4);          \
      a5 = fmaf(X##p.x, cF.x, a5); a5 = fmaf(X##p.y, cF.y, a5);          \
      a5 = fmaf(X##p.z, cF.z, a5); a5 = fmaf(X##p.w, cF.w, a5);          \
      a6 = fmaf(X##p.x, cG.x, a6); a6 = fmaf(X##p.y, cG.y, a6);          \
      a6 = fmaf(X##p.z, cG.z, a6); a6 = fmaf(X##p.w, cG.w, a6);          \
      a7 = fmaf(X##p.x, cH.x, a7); a7 = fmaf(X##p.y, cH.y, a7);          \
      a7 = fmaf(X##p.z, cH.z, a7); a7 = fmaf(X##p.w, cH.w, a7); }
    D4STEP(0) D4STEP(1) D4STEP(2) D4STEP(3)
    D4STEP(4) D4STEP(5) D4STEP(6) D4STEP(7)
    D4STEP(8) D4STEP(9) D4STEP(10) D4STEP(11)
    D4STEP(12) D4STEP(13) D4STEP(14) D4STEP(15)
#undef D4STEP
#undef FMA4
    // d2 = (x2 - 2M) + c2, strict < with ascending k keeps np first index.
#define FIN(j)                                                \
    { const float c2v = c2g[k0 + j];                          \
      const float s = (xn2 - 2.0f * a##j) + c2v;              \
      if (s < m1) { m1 = s; i1 = k0 + j; } }
    FIN(0) FIN(1) FIN(2) FIN(3) FIN(4) FIN(5) FIN(6) FIN(7)
#undef FIN
  }

  out_codes[row] = (float)i1;   // coalesced
  atomicAdd(&bins[i1], 1);

  // fused outputs: gather q (codebook L1/L2-hot), STE write, fp64 loss partial.
  double dacc = 0.0;
  const float4* q4 = cb4 + (size_t)i1 * 16;  // per-lane divergent, cache-hot
  float4* o4 = (float4*)(out_st + (size_t)row * DIMS);
#define EPI(p)                                                            \
  { const float4 q = q4[p]; float4 o;                                     \
    o.x = X##p.x + (q.x - X##p.x); o.y = X##p.y + (q.y - X##p.y);         \
    o.z = X##p.z + (q.z - X##p.z); o.w = X##p.w + (q.w - X##p.w);         \
    o4[p] = o;                                                            \
    const float dx = X##p.x - q.x, dy = X##p.y - q.y;                     \
    const float dz = X##p.z - q.z, dw = X##p.w - q.w;                     \
    dacc += (double)dx * (double)dx; dacc += (double)dy * (double)dy;     \
    dacc += (double)dz * (double)dz; dacc += (double)dw * (double)dw; }
  EPI(0) EPI(1) EPI(2) EPI(3) EPI(4) EPI(5) EPI(6) EPI(7)
  EPI(8) EPI(9) EPI(10) EPI(11) EPI(12) EPI(13) EPI(14) EPI(15)
#undef EPI

  #pragma unroll
  for (int off = 32; off > 0; off >>= 1) dacc += __shfl_down(dacc, off);
  __shared__ double wsum[4];
  if ((t & 63) == 0) wsum[t >> 6] = dacc;
  __syncthreads();
  if (t == 0) loss_part[blockIdx.x] = wsum[0] + wsum[1] + wsum[2] + wsum[3];
}

// ---------------- K2: reduce loss partials + perplexity + scalar outputs ----------
__global__ __launch_bounds__(512) void vq_finalize(const int* __restrict__ bins,
                                                   const double* __restrict__ loss_part,
                                                   float* __restrict__ out3) {
  __shared__ double red[512];
  __shared__ double redl[512];
  const int t = threadIdx.x;
  const double p = (double)bins[t] / 131072.0;
  red[t] = -p * log(p + 1e-10);
  redl[t] = loss_part[t];
  __syncthreads();
  for (int s = 256; s > 0; s >>= 1) {
    if (t < s) { red[t] += red[t + s]; redl[t] += redl[t + s]; }
    __syncthreads();
  }
  if (t == 0) {
    const double mean = redl[0] / 8388608.0;
    out3[0] = (float)(0.25 * mean);  // commitment * COMMITMENT_COST
    out3[1] = (float)mean;           // codebook_loss (same squares bitwise)
    out3[2] = (float)exp(red[0]);    // perplexity
  }
}

extern "C" void kernel_launch(void* const* d_in, const int* in_sizes, int n_in,
                              void* d_out, int out_size, void* d_ws, size_t ws_size,
                              hipStream_t stream) {
  const float* latents = (const float*)d_in[0];
  const float* codebook = (const float*)d_in[1];

  float* out = (float*)d_out;
  float* out_st = out;                                   // 8388608
  float* out_codes = out + (size_t)N_ROWS * DIMS;        // 131072 (codes as float)
  float* out3 = out_codes + N_ROWS;                      // 3 scalars

  char* ws = (char*)d_ws;
  double* loss_part = (double*)ws;               // [0, 4096)   512 slots
  int* bins = (int*)(ws + 4096);                 // [4096, 6144)
  float* c2g = (float*)(ws + 6144);              // [6144, 8192)

  hipLaunchKernelGGL(vq_init, dim3(1), dim3(256), 0, stream,
                     codebook, bins, c2g);
  hipLaunchKernelGGL(vq_argmin, dim3(ARG_BLOCKS), dim3(256), 0, stream,
                     latents, codebook, c2g, out_codes, bins, out_st, loss_part);
  hipLaunchKernelGGL(vq_finalize, dim3(1), dim3(512), 0, stream,
                     bins, loss_part, out3);
}

// Round 8
// 352.161 us; speedup vs baseline: 1.3295x; 1.1093x over previous
//
#include <hip/hip_runtime.h>
#include <math.h>

#define N_ROWS 131072
#define DIMS 64
#define K_CODES 512
#define OUT_BLOCKS 1024
#define TAU 1e-4f

typedef _Float16 v8h __attribute__((ext_vector_type(8)));
typedef float v4f __attribute__((ext_vector_type(4)));

// ---------------- K0: zero bins/flags + c2 (np-pairwise, bitwise) + fp16 split codebook ----
// Split: c' = 1024*c (exact-scale into fp16-normal range) = chi + clo, |err| ~ 2^-22 |c'|.
__global__ __launch_bounds__(256) void vq_init(const float* __restrict__ codebook,
                                               int* __restrict__ bins,
                                               float* __restrict__ c2g,
                                               _Float16* __restrict__ chi,
                                               _Float16* __restrict__ clo,
                                               int* __restrict__ flags32) {
  #pragma clang fp contract(off)
  const int g = blockIdx.x * 256 + threadIdx.x;  // 16 blocks -> g in [0,4096)
  if (g < K_CODES) {
    bins[g] = 0;
    const float* cr = codebook + g * DIMS;
    float r0 = cr[0] * cr[0], r1 = cr[1] * cr[1], r2 = cr[2] * cr[2], r3 = cr[3] * cr[3];
    float r4 = cr[4] * cr[4], r5 = cr[5] * cr[5], r6 = cr[6] * cr[6], r7 = cr[7] * cr[7];
    for (int i = 8; i < 64; i += 8) {
      r0 += cr[i + 0] * cr[i + 0]; r1 += cr[i + 1] * cr[i + 1];
      r2 += cr[i + 2] * cr[i + 2]; r3 += cr[i + 3] * cr[i + 3];
      r4 += cr[i + 4] * cr[i + 4]; r5 += cr[i + 5] * cr[i + 5];
      r6 += cr[i + 6] * cr[i + 6]; r7 += cr[i + 7] * cr[i + 7];
    }
    c2g[g] = ((r0 + r1) + (r2 + r3)) + ((r4 + r5) + (r6 + r7));
  }
  for (int i = g; i < N_ROWS / 4; i += 4096) flags32[i] = 0;  // 128KB flag bytes
  for (int i = g; i < K_CODES * DIMS; i += 4096) {
    const float cv = codebook[i] * 1024.0f;
    const _Float16 h = (_Float16)cv;
    chi[i] = h;
    clo[i] = (_Float16)(cv - (float)h);
  }
}

// ---------------- K1 phase A: fp16-split MFMA scores + online top-2 + flag near-ties ------
// Wave owns 64 rows (4 rowblocks of 16). A-frag (x) layout: A[m=lane&15][k=quad*8+j],
// K=64 as 2 ksteps of 32. B-frag: n=lane&15 (code), k=quad*8+j (d). C/D: col=lane&15
// (code), row=quad*4+reg. 3 MFMAs/kstep: xh*ch + xh*cl + xl*ch -> acc ~= 1024*(x.c)
// to ~3e-7 abs. s_hp = fmaf(acc, -2^-9, c2) (== c2 - 2 x.c). Rows whose HP top-2 gap
// < TAU go to exact np recheck; for the rest HP argmin == np argmin (error bounds:
// np rounding <= ~1.6e-5, HP err <= ~3e-5 incl. fp16-denorm worst case; TAU=1e-4).
__global__ __launch_bounds__(256) void vq_phaseA(const float* __restrict__ latents,
                                                 const _Float16* __restrict__ chi,
                                                 const _Float16* __restrict__ clo,
                                                 const float* __restrict__ c2g,
                                                 float* __restrict__ out_codes,
                                                 unsigned char* __restrict__ flags) {
  #pragma clang fp contract(off)
  const int t = threadIdx.x;
  const int lane = t & 63;
  const int m16 = lane & 15;
  const int quad = lane >> 4;
  const int rowbase = (blockIdx.x * 4 + (t >> 6)) * 64;

#define CVT(H, L, i, val) \
  { const float fv_ = (val); const _Float16 hh_ = (_Float16)fv_; \
    H[i] = hh_; L[i] = (_Float16)(fv_ - (float)hh_); }

#define LOADA(rb, ks) \
  v8h Ah_##rb##_##ks, Al_##rb##_##ks; \
  { const float* xp = latents + (size_t)(rowbase + rb * 16 + m16) * DIMS + (ks * 32 + quad * 8); \
    const float4 f0 = *(const float4*)xp; \
    const float4 f1 = *(const float4*)(xp + 4); \
    CVT(Ah_##rb##_##ks, Al_##rb##_##ks, 0, f0.x) \
    CVT(Ah_##rb##_##ks, Al_##rb##_##ks, 1, f0.y) \
    CVT(Ah_##rb##_##ks, Al_##rb##_##ks, 2, f0.z) \
    CVT(Ah_##rb##_##ks, Al_##rb##_##ks, 3, f0.w) \
    CVT(Ah_##rb##_##ks, Al_##rb##_##ks, 4, f1.x) \
    CVT(Ah_##rb##_##ks, Al_##rb##_##ks, 5, f1.y) \
    CVT(Ah_##rb##_##ks, Al_##rb##_##ks, 6, f1.z) \
    CVT(Ah_##rb##_##ks, Al_##rb##_##ks, 7, f1.w) }

  LOADA(0, 0) LOADA(0, 1) LOADA(1, 0) LOADA(1, 1)
  LOADA(2, 0) LOADA(2, 1) LOADA(3, 0) LOADA(3, 1)
#undef LOADA
#undef CVT

  const float INF = __builtin_inff();
#define DECLS(rb) \
  float m1_##rb##_0 = INF, m1_##rb##_1 = INF, m1_##rb##_2 = INF, m1_##rb##_3 = INF; \
  float m2_##rb##_0 = INF, m2_##rb##_1 = INF, m2_##rb##_2 = INF, m2_##rb##_3 = INF; \
  int i1_##rb##_0 = 0, i1_##rb##_1 = 0, i1_##rb##_2 = 0, i1_##rb##_3 = 0;
  DECLS(0) DECLS(1) DECLS(2) DECLS(3)
#undef DECLS

#define UPD(rb, r) \
  { const float s = fmaf(acc[r], -0x1p-9f, c2v); \
    if (s < m1_##rb##_##r) { m2_##rb##_##r = m1_##rb##_##r; m1_##rb##_##r = s; i1_##rb##_##r = code; } \
    else if (s < m2_##rb##_##r) { m2_##rb##_##r = s; } }
#define MM(rb) \
  { v4f acc = {0.f, 0.f, 0.f, 0.f}; \
    acc = __builtin_amdgcn_mfma_f32_16x16x32_f16(Ah_##rb##_0, Bh0, acc, 0, 0, 0); \
    acc = __builtin_amdgcn_mfma_f32_16x16x32_f16(Ah_##rb##_0, Bl0, acc, 0, 0, 0); \
    acc = __builtin_amdgcn_mfma_f32_16x16x32_f16(Al_##rb##_0, Bh0, acc, 0, 0, 0); \
    acc = __builtin_amdgcn_mfma_f32_16x16x32_f16(Ah_##rb##_1, Bh1, acc, 0, 0, 0); \
    acc = __builtin_amdgcn_mfma_f32_16x16x32_f16(Ah_##rb##_1, Bl1, acc, 0, 0, 0); \
    acc = __builtin_amdgcn_mfma_f32_16x16x32_f16(Al_##rb##_1, Bh1, acc, 0, 0, 0); \
    UPD(rb, 0) UPD(rb, 1) UPD(rb, 2) UPD(rb, 3) }

  #pragma unroll 1
  for (int nt = 0; nt < 32; ++nt) {
    const int code = nt * 16 + m16;
    const _Float16* bp = chi + (size_t)code * DIMS + quad * 8;
    const _Float16* lp = clo + (size_t)code * DIMS + quad * 8;
    const v8h Bh0 = *(const v8h*)bp;
    const v8h Bh1 = *(const v8h*)(bp + 32);
    const v8h Bl0 = *(const v8h*)lp;
    const v8h Bl1 = *(const v8h*)(lp + 32);
    const float c2v = c2g[code];
    MM(0) MM(1) MM(2) MM(3)
  }
#undef MM
#undef UPD

  // merge top-2 across the 16 col-lanes (same quad); value tie -> smaller code index
#define MERGE(rb, r) \
  { float v = m1_##rb##_##r, v2 = m2_##rb##_##r; int idx = i1_##rb##_##r; \
    for (int off = 1; off < 16; off <<= 1) { \
      const float ov = __shfl_xor(v, off); \
      const float ov2 = __shfl_xor(v2, off); \
      const int oi = __shfl_xor(idx, off); \
      const float hi = fmaxf(v, ov); \
      if (ov < v || (ov == v && oi < idx)) { v = ov; idx = oi; } \
      v2 = fminf(fminf(v2, ov2), hi); } \
    if (m16 == 0) { \
      const int row = rowbase + rb * 16 + quad * 4 + r; \
      out_codes[row] = (float)idx; \
      if (v2 - v < TAU) flags[row] = 1; } }
  MERGE(0, 0) MERGE(0, 1) MERGE(0, 2) MERGE(0, 3)
  MERGE(1, 0) MERGE(1, 1) MERGE(1, 2) MERGE(1, 3)
  MERGE(2, 0) MERGE(2, 1) MERGE(2, 2) MERGE(2, 3)
  MERGE(3, 0) MERGE(3, 1) MERGE(3, 2) MERGE(3, 3)
#undef MERGE
}

// ---------------- K2 phase B: np-bitwise exact argmin for flagged rows -------------
// Wave per flagged row; lane evaluates codes lane*8..+7 (ascending -> strict < keeps
// first index); 64-lane merge with value tie -> min index == np first-index.
// Numerics identical to the verified r2/r7 chain.
__global__ __launch_bounds__(256) void vq_recheck(const float* __restrict__ latents,
                                                  const float* __restrict__ codebook,
                                                  const float* __restrict__ c2g,
                                                  float* __restrict__ out_codes,
                                                  const int* __restrict__ flags32) {
  #pragma clang fp contract(off)
  const int t = threadIdx.x;
  const int lane = t & 63;
  const int wid = blockIdx.x * 4 + (t >> 6);  // 128 blocks -> 512 waves
  const int base = wid * 256;                 // each wave owns 256 contiguous rows
  const int myw = flags32[wid * 64 + lane];   // 64 ints = 256 flag bytes, one coalesced load
  const float4* cb4 = (const float4*)codebook;

  for (int r = 0; r < 256; ++r) {
    const int fw = __shfl(myw, r >> 2);
    if (((fw >> ((r & 3) * 8)) & 0xff) == 0) continue;
    const int row = base + r;

    const float4* xr = (const float4*)(latents + (size_t)row * DIMS);
#define LOADX(p) const float4 X##p = xr[p];
    LOADX(0) LOADX(1) LOADX(2) LOADX(3) LOADX(4) LOADX(5) LOADX(6) LOADX(7)
    LOADX(8) LOADX(9) LOADX(10) LOADX(11) LOADX(12) LOADX(13) LOADX(14) LOADX(15)
#undef LOADX
    // np pairwise x2 (verified r7 pattern)
    float r0 = X0.x * X0.x, r1 = X0.y * X0.y, r2 = X0.z * X0.z, r3 = X0.w * X0.w;
    float r4 = X1.x * X1.x, r5 = X1.y * X1.y, r6 = X1.z * X1.z, r7 = X1.w * X1.w;
#define ACC8(A, B)                                                    \
    r0 += A.x * A.x; r1 += A.y * A.y; r2 += A.z * A.z; r3 += A.w * A.w; \
    r4 += B.x * B.x; r5 += B.y * B.y; r6 += B.z * B.z; r7 += B.w * B.w;
    ACC8(X2, X3) ACC8(X4, X5) ACC8(X6, X7) ACC8(X8, X9)
    ACC8(X10, X11) ACC8(X12, X13) ACC8(X14, X15)
#undef ACC8
    const float xn2 = ((r0 + r1) + (r2 + r3)) + ((r4 + r5) + (r6 + r7));

    float best = __builtin_inff();
    int bidx = 0x7fffffff;
#define STEP(p)                                   \
    { const float4 c = cr[p];                     \
      acc = fmaf(X##p.x, c.x, acc);               \
      acc = fmaf(X##p.y, c.y, acc);               \
      acc = fmaf(X##p.z, c.z, acc);               \
      acc = fmaf(X##p.w, c.w, acc); }
    #pragma unroll 1
    for (int j = 0; j < 8; ++j) {
      const int k = lane * 8 + j;
      const float4* cr = cb4 + (size_t)k * 16;   // per-lane, L2-hot
      float acc = 0.f;
      STEP(0) STEP(1) STEP(2) STEP(3) STEP(4) STEP(5) STEP(6) STEP(7)
      STEP(8) STEP(9) STEP(10) STEP(11) STEP(12) STEP(13) STEP(14) STEP(15)
      const float s = (xn2 - 2.0f * acc) + c2g[k];
      if (s < best) { best = s; bidx = k; }
    }
#undef STEP
    for (int off = 1; off < 64; off <<= 1) {
      const float ov = __shfl_xor(best, off);
      const int oi = __shfl_xor(bidx, off);
      if (ov < best || (ov == best && oi < bidx)) { best = ov; bidx = oi; }
    }
    if (lane == 0) out_codes[row] = (float)bidx;
  }
}

// ---------------- K3: gather + STE + loss partials + bins (r3-verified body) --------
__global__ __launch_bounds__(256) void vq_outputs(const float* __restrict__ latents,
                                                  const float* __restrict__ codebook,
                                                  const float* __restrict__ out_codes,
                                                  float* __restrict__ out_st,
                                                  double* __restrict__ loss_part,
                                                  int* __restrict__ bins) {
  #pragma clang fp contract(off)
  const int t = threadIdx.x;
  const int nvec4 = N_ROWS * DIMS / 4;
  double acc = 0.0;
  for (int v4 = blockIdx.x * 256 + t; v4 < nvec4; v4 += OUT_BLOCKS * 256) {
    const int row = v4 >> 4;
    const int dq = v4 & 15;
    const int k = (int)out_codes[row];
    const float4 l = ((const float4*)latents)[v4];
    const float4 q = ((const float4*)codebook)[k * 16 + dq];
    float4 o;
    o.x = l.x + (q.x - l.x);
    o.y = l.y + (q.y - l.y);
    o.z = l.z + (q.z - l.z);
    o.w = l.w + (q.w - l.w);
    ((float4*)out_st)[v4] = o;
    const float dx = l.x - q.x, dy = l.y - q.y, dz = l.z - q.z, dw = l.w - q.w;
    acc += (double)dx * (double)dx;
    acc += (double)dy * (double)dy;
    acc += (double)dz * (double)dz;
    acc += (double)dw * (double)dw;
    if (dq == 0) atomicAdd(&bins[k], 1);
  }
  #pragma unroll
  for (int off = 32; off > 0; off >>= 1) acc += __shfl_down(acc, off);
  __shared__ double wsum[4];
  if ((t & 63) == 0) wsum[t >> 6] = acc;
  __syncthreads();
  if (t == 0) loss_part[blockIdx.x] = wsum[0] + wsum[1] + wsum[2] + wsum[3];
}

// ---------------- K4: reduce loss partials + perplexity + scalars ----------
__global__ __launch_bounds__(512) void vq_finalize(const int* __restrict__ bins,
                                                   const double* __restrict__ loss_part,
                                                   float* __restrict__ out3) {
  __shared__ double red[512];
  __shared__ double redl[512];
  const int t = threadIdx.x;
  const double p = (double)bins[t] / 131072.0;
  red[t] = -p * log(p + 1e-10);
  redl[t] = loss_part[t] + loss_part[t + 512];
  __syncthreads();
  for (int s = 256; s > 0; s >>= 1) {
    if (t < s) { red[t] += red[t + s]; redl[t] += redl[t + s]; }
    __syncthreads();
  }
  if (t == 0) {
    const double mean = redl[0] / 8388608.0;
    out3[0] = (float)(0.25 * mean);
    out3[1] = (float)mean;
    out3[2] = (float)exp(red[0]);
  }
}

extern "C" void kernel_launch(void* const* d_in, const int* in_sizes, int n_in,
                              void* d_out, int out_size, void* d_ws, size_t ws_size,
                              hipStream_t stream) {
  const float* latents = (const float*)d_in[0];
  const float* codebook = (const float*)d_in[1];

  float* out = (float*)d_out;
  float* out_st = out;                                // 8388608
  float* out_codes = out + (size_t)N_ROWS * DIMS;     // 131072 (codes as float)
  float* out3 = out_codes + N_ROWS;                   // 3 scalars

  char* ws = (char*)d_ws;
  double* loss_part = (double*)ws;                    // [0, 8192)       1024 slots
  int* bins = (int*)(ws + 8192);                      // [8192, 10240)
  float* c2g = (float*)(ws + 10240);                  // [10240, 12288)
  _Float16* chi = (_Float16*)(ws + 12288);            // [12288, 77824)  64KB
  _Float16* clo = (_Float16*)(ws + 77824);            // [77824, 143360) 64KB
  unsigned char* flags = (unsigned char*)(ws + 143360);  // 128KB flag bytes
  int* flags32 = (int*)(ws + 143360);

  hipLaunchKernelGGL(vq_init, dim3(16), dim3(256), 0, stream,
                     codebook, bins, c2g, chi, clo, flags32);
  hipLaunchKernelGGL(vq_phaseA, dim3(N_ROWS / 256), dim3(256), 0, stream,
                     latents, chi, clo, c2g, out_codes, flags);
  hipLaunchKernelGGL(vq_recheck, dim3(128), dim3(256), 0, stream,
                     latents, codebook, c2g, out_codes, flags32);
  hipLaunchKernelGGL(vq_outputs, dim3(OUT_BLOCKS), dim3(256), 0, stream,
                     latents, codebook, out_codes, out_st, loss_part, bins);
  hipLaunchKernelGGL(vq_finalize, dim3(1), dim3(512), 0, stream,
                     bins, loss_part, out3);
}